// Round 7
// baseline (39543.988 us; speedup 1.0000x reference)
//
#include <hip/hip_runtime.h>
#include <hip/hip_bf16.h>

// TrainerRNN: 10-layer GRU (T=2048, IN=384, H=768) + linear head (384).
// ROUND 6: critical-path restructure of R5 (2-group, 2-tick-skew pipeline,
// 10250 global barriers, fence-free sc1 coherence). R5 tick = 2.48 us; the
// shadow-prefetch did its FMAs between arrive and scan, overshooting the
// release window by ~0.4 us. Now:
//  - prefetch = raw 64-bit packed sc1 LOADS into g2[] (no FMA), issued after
//    arrive; they complete during the counter scan.
//  - after release: issue h-row loads FIRST, then gi FMAs from g2 (hidden
//    under h-load latency), then h FMAs, butterfly, gates, packed store.
//  - all 3 waves scan independently -> single __syncthreads per tick (the
//    pre-arrive one, which also drains each wave's sc1 stores via vmcnt(0)).
//  - lane k-mapping: k = 2*lane + 128*kk (64-bit loads; LDS reads stay
//    conflict-benign: 2-way aliasing is free on gfx950).

#define T_SEQ 2048
#define H_DIM 768
#define IN0   384
#define G3    2304
#define NPHASE 5
#define PHASE_TICKS (T_SEQ + 2)
#define NBLK  256
#define HALF  128
#define NTHR  192       // 3 waves; 2 units per wave; 6 units per block
#define NOUT  384
#define CTR_STRIDE 32   // counters 128 B apart

__device__ __forceinline__ float sigm(float x) { return 1.0f / (1.0f + __expf(-x)); }

__device__ __forceinline__ float2 ldg2(const float* p) {
    unsigned long long v = __hip_atomic_load((const unsigned long long*)p,
        __ATOMIC_RELAXED, __HIP_MEMORY_SCOPE_AGENT);
    union { unsigned long long u; float2 f; } c; c.u = v; return c.f;
}
__device__ __forceinline__ void stg2(float* p, float2 v) {
    union { float2 f; unsigned long long u; } c; c.f = v;
    __hip_atomic_store((unsigned long long*)p, c.u,
        __ATOMIC_RELAXED, __HIP_MEMORY_SCOPE_AGENT);
}

extern "C" __global__ __launch_bounds__(NTHR, 1) void gru_pair(
    const float* __restrict__ x,
    const float* __restrict__ wih0,
    const float* __restrict__ whh0,
    const float* __restrict__ bih0,
    const float* __restrict__ bhh0,
    const float* __restrict__ wihS,
    const float* __restrict__ whhS,
    const float* __restrict__ bihS,
    const float* __restrict__ bhhS,
    float* __restrict__ b0, float* __restrict__ b1, float* __restrict__ b2,
    unsigned int* __restrict__ ctr)
{
    __shared__ float lds[6 * 4608];        // 110.6 KB

    const int tid  = threadIdx.x;
    const int lane = tid & 63;
    const int wv   = tid >> 6;             // 0..2
    const int bid  = blockIdx.x;
    const bool isA = (bid < HALF);
    const int skew = isA ? 0 : 2;
    const int gb   = isA ? bid : bid - HALF;   // group-local block id
    float* bufs[3] = { b0, b1, b2 };
    unsigned int gstep = 0;

    for (int p = 0; p < NPHASE; ++p) {
        const int layer = 2 * p + (isA ? 0 : 1);
        const int Din   = (layer == 0) ? IN0 : H_DIM;
        const int ndk   = (layer == 0) ? 3 : 6;     // 128-wide chunks of Din
        const float* wih = (layer == 0) ? wih0 : wihS + (size_t)(layer - 1) * G3 * H_DIM;
        const float* whh = (layer == 0) ? whh0 : whhS + (size_t)(layer - 1) * G3 * H_DIM;
        const float* bih = (layer == 0) ? bih0 : bihS + (size_t)(layer - 1) * G3;
        const float* bhh = (layer == 0) ? bhh0 : bhhS + (size_t)(layer - 1) * G3;
        float*       yc = bufs[layer % 3];                          // my layer's h
        const float* yg = (layer == 0) ? x : bufs[(layer - 1) % 3]; // gi source
        const int girow = (layer == 0) ? IN0 : H_DIM;               // gi row stride

        const int j0 = gb * 6 + wv * 2;    // first of my 2 units (even)
        const int ustride = 3 * Din + 3 * H_DIM;
        float* L = lds + (wv * 2) * ustride;

        // ---- stage 2 units' weight rows into LDS ----
        for (int u = 0; u < 2; ++u) {
            for (int g = 0; g < 3; ++g) {
                const float4* src = (const float4*)(wih + (size_t)(j0 + u + g * H_DIM) * Din);
                float4* dst = (float4*)(L + u * ustride + g * Din);
                for (int k = lane; k < Din / 4; k += 64) dst[k] = src[k];
            }
            for (int g = 0; g < 3; ++g) {
                const float4* src = (const float4*)(whh + (size_t)(j0 + u + g * H_DIM) * H_DIM);
                float4* dst = (float4*)(L + u * ustride + 3 * Din + g * H_DIM);
                for (int k = lane; k < H_DIM / 4; k += 64) dst[k] = src[k];
            }
        }
        float bir[2], biz[2], bin_[2], bhr[2], bhz[2], bhn[2];
        for (int u = 0; u < 2; ++u) {
            bir[u] = bih[j0 + u];        biz[u] = bih[j0 + u + 768];
            bin_[u] = bih[j0 + u + 1536];
            bhr[u] = bhh[j0 + u];        bhz[u] = bhh[j0 + u + 768];
            bhn[u] = bhh[j0 + u + 1536];
        }
        __syncthreads();

        const float *Lr[2], *Lz[2], *Ln[2], *Hr[2], *Hz[2], *Hn[2];
        for (int u = 0; u < 2; ++u) {
            const float* B = L + u * ustride;
            Lr[u] = B;            Lz[u] = B + Din;       Ln[u] = B + 2 * Din;
            Hr[u] = B + 3 * Din;  Hz[u] = Hr[u] + H_DIM; Hn[u] = Hz[u] + H_DIM;
        }

        // ---- gi prefetch (loads only) for iteration 0: A's source is x /
        //      the fully-written previous-phase buffer ----
        float2 g2[6];
        if (isA) {
            for (int kk = 0; kk < ndk; ++kk)
                g2[kk] = ldg2(yg + 2 * lane + 128 * kk);
        }

        for (int m = 0; m < PHASE_TICKS; ++m) {
            const int t = m - skew;
            const bool act = (t >= 0) && (t < T_SEQ);

            if (act) {
                // ---- issue h-row loads FIRST (critical path) ----
                float2 h2[6];
                float2 hp2 = make_float2(0.f, 0.f);
                if (t > 0) {
                    const float* hr = yc + (size_t)(t - 1) * H_DIM;
                    hp2 = ldg2(hr + j0);
#pragma unroll
                    for (int kk = 0; kk < 6; ++kk)
                        h2[kk] = ldg2(hr + 2 * lane + 128 * kk);
                }

                // ---- gi FMAs from prefetched registers (hide h latency) ----
                float s0 = 0.f, s1 = 0.f, s2 = 0.f, s3 = 0.f;
                float s4 = 0.f, s5 = 0.f, s6 = 0.f, s7 = 0.f;
                for (int kk = 0; kk < ndk; ++kk) {
                    const int k = 2 * lane + 128 * kk;
                    const float a = g2[kk].x, b = g2[kk].y;
                    s0 += a * Lr[0][k] + b * Lr[0][k + 1];
                    s4 += a * Lr[1][k] + b * Lr[1][k + 1];
                    s1 += a * Lz[0][k] + b * Lz[0][k + 1];
                    s5 += a * Lz[1][k] + b * Lz[1][k + 1];
                    s2 += a * Ln[0][k] + b * Ln[0][k + 1];
                    s6 += a * Ln[1][k] + b * Ln[1][k + 1];
                }

                // ---- h FMAs ----
                if (t > 0) {
#pragma unroll
                    for (int kk = 0; kk < 6; ++kk) {
                        const int k = 2 * lane + 128 * kk;
                        const float a = h2[kk].x, b = h2[kk].y;
                        s0 += a * Hr[0][k] + b * Hr[0][k + 1];
                        s4 += a * Hr[1][k] + b * Hr[1][k + 1];
                        s1 += a * Hz[0][k] + b * Hz[0][k + 1];
                        s5 += a * Hz[1][k] + b * Hz[1][k + 1];
                        s3 += a * Hn[0][k] + b * Hn[0][k + 1];
                        s7 += a * Hn[1][k] + b * Hn[1][k + 1];
                    }
                }

#pragma unroll
                for (int off = 32; off > 0; off >>= 1) {
                    s0 += __shfl_xor(s0, off, 64); s1 += __shfl_xor(s1, off, 64);
                    s2 += __shfl_xor(s2, off, 64); s3 += __shfl_xor(s3, off, 64);
                    s4 += __shfl_xor(s4, off, 64); s5 += __shfl_xor(s5, off, 64);
                    s6 += __shfl_xor(s6, off, 64); s7 += __shfl_xor(s7, off, 64);
                }

                if (lane == 0) {
                    const float r0 = sigm(s0 + bir[0] + bhr[0]);
                    const float z0 = sigm(s1 + biz[0] + bhz[0]);
                    const float n0 = tanhf(s2 + bin_[0] + r0 * (s3 + bhn[0]));
                    const float r1 = sigm(s4 + bir[1] + bhr[1]);
                    const float z1 = sigm(s5 + biz[1] + bhz[1]);
                    const float n1 = tanhf(s6 + bin_[1] + r1 * (s7 + bhn[1]));
                    stg2(&yc[(size_t)t * H_DIM + j0],
                         make_float2((1.f - z0) * n0 + z0 * hp2.x,
                                     (1.f - z1) * n1 + z1 * hp2.y));
                }
            }

            // ---- arrive: syncthreads drains all waves' sc1 stores ----
            __syncthreads();
            ++gstep;
            if (tid == 0)
                __hip_atomic_fetch_add(&ctr[(bid >> 2) * CTR_STRIDE], 1u,
                                       __ATOMIC_RELAXED, __HIP_MEMORY_SCOPE_AGENT);

            // ---- gi prefetch for m+1: LOADS ONLY (complete during scan).
            //      A: row m+1 of prev-phase buffer / x (always published).
            //      B: row m-1, published at barrier m-1. ----
            const int tn = m + 1 - skew;
            if (tn >= 0 && tn < T_SEQ) {
                const float* xr = yg + (size_t)tn * girow;
                for (int kk = 0; kk < ndk; ++kk)
                    g2[kk] = ldg2(xr + 2 * lane + 128 * kk);
            }

            // ---- all 3 waves scan independently; no trailing sync ----
            {
                const unsigned int tgt = 4u * gstep;
                for (;;) {
                    const unsigned int v = __hip_atomic_load(
                        &ctr[lane * CTR_STRIDE],
                        __ATOMIC_RELAXED, __HIP_MEMORY_SCOPE_AGENT);
                    if (__all(v >= tgt)) break;
                    __builtin_amdgcn_s_sleep(1);
                }
            }
        }
    }
}

extern "C" __global__ __launch_bounds__(NOUT, 1) void fc_head(
    const float* __restrict__ h,
    const float* __restrict__ fw,
    const float* __restrict__ fb,
    float* __restrict__ out)
{
    __shared__ float hs[H_DIM];
    const int t = blockIdx.x;
    const float* hr = h + (size_t)t * H_DIM;
    for (int k = threadIdx.x; k < H_DIM; k += NOUT) hs[k] = hr[k];
    __syncthreads();

    const int o = threadIdx.x;
    float acc = fb[o];
    const float* wr = fw + (size_t)o * H_DIM;
#pragma unroll 8
    for (int k = 0; k < H_DIM; ++k) acc += hs[k] * wr[k];
    out[(size_t)t * NOUT + o] = acc;
}

extern "C" void kernel_launch(void* const* d_in, const int* in_sizes, int n_in,
                              void* d_out, int out_size, void* d_ws, size_t ws_size,
                              hipStream_t stream)
{
    const float* x    = (const float*)d_in[0];
    const float* wih0 = (const float*)d_in[1];
    const float* whh0 = (const float*)d_in[2];
    const float* bih0 = (const float*)d_in[3];
    const float* bhh0 = (const float*)d_in[4];
    const float* wihS = (const float*)d_in[5];
    const float* whhS = (const float*)d_in[6];
    const float* bihS = (const float*)d_in[7];
    const float* bhhS = (const float*)d_in[8];
    const float* fcw  = (const float*)d_in[9];
    const float* fcb  = (const float*)d_in[10];

    char* ws = (char*)d_ws;
    unsigned int* ctr = (unsigned int*)ws;          // 64 padded group counters
    float* b0 = (float*)(ws + 65536);               // 3 x [2048,768] fp32
    float* b1 = b0 + (size_t)T_SEQ * H_DIM;
    float* b2 = b1 + (size_t)T_SEQ * H_DIM;

    hipMemsetAsync(ctr, 0, 65536, stream);          // zero counters

    hipLaunchKernelGGL(gru_pair, dim3(NBLK), dim3(NTHR), 0, stream,
                       x, wih0, whh0, bih0, bhh0, wihS, whhS, bihS, bhhS,
                       b0, b1, b2, ctr);

    // layer 9 -> buf[9 % 3] = b0
    hipLaunchKernelGGL(fc_head, dim3(T_SEQ), dim3(NOUT), 0, stream,
                       b0, fcw, fcb, (float*)d_out);
}